// Round 14
// baseline (160.919 us; speedup 1.0000x reference)
//
#include <hip/hip_runtime.h>

#define IH 512
#define IW 512
#define OH 510
#define OW 510
#define NB 32
#define KO 16
#define OHW (OH * OW)
#define PPB 8              // planes per block (o-half)
#define LO 1020            // floats per plane-region (2 rows x 510)
#define TQ 15              // row-pair tiles per block (17 bands * 15 = 255)
#define NBAND 17

typedef float f32x4 __attribute__((ext_vector_type(4)));
typedef float f32x2 __attribute__((ext_vector_type(2)));

// R14: R13's LDS-bounce + multi-tile pipeline with RAW barriers so stores are
// NEVER drained inside the loop. __syncthreads would emit s_waitcnt vmcnt(0)
// (m97 barrier drain) killing store flow; raw s_barrier + explicit lgkmcnt(0)
// leaves stores in flight -> tile q's stores drain under tile q+1's FMA.
// Loads are issued BEFORE stores each iter so the compiler's auto vmcnt wait
// for load data is counted (leaves the 8 stores outstanding), never 0.
// Double-buffered LDS (2 x 8 planes x 1020 = 65,280B) -> 2 blocks/CU.

__device__ __forceinline__ void load_xv(const float* __restrict__ xr,
                                        bool tail, float v[3][6])
{
#pragma unroll
    for (int r = 0; r < 3; ++r) {
        const float2 a = *reinterpret_cast<const float2*>(xr + r * IW);
        const float2 b = *reinterpret_cast<const float2*>(xr + r * IW + 2);
        v[r][0] = a.x; v[r][1] = a.y; v[r][2] = b.x; v[r][3] = b.y;
        if (!tail) {
            const float2 c = *reinterpret_cast<const float2*>(xr + r * IW + 4);
            v[r][4] = c.x; v[r][5] = c.y;
        } else {
            v[r][4] = 0.0f; v[r][5] = 0.0f;
        }
    }
}

__device__ __forceinline__ void fma_to_lds(const float xv[3][6],
                                           const float* __restrict__ k,
                                           int ob, float* __restrict__ buf,
                                           int lbase, bool tail)
{
#pragma unroll
    for (int ol = 0; ol < PPB; ++ol) {
        const int o = ob + ol;
        float a0 = 0.f, a1 = 0.f, a2 = 0.f, a3 = 0.f;
#pragma unroll
        for (int r = 0; r < 3; ++r)
#pragma unroll
            for (int c = 0; c < 3; ++c) {
                const float kv = k[(o * 3 + r) * 3 + c];  // uniform -> s_load
                a0 = fmaf(xv[r][c],     kv, a0);
                a1 = fmaf(xv[r][c + 1], kv, a1);
                a2 = fmaf(xv[r][c + 2], kv, a2);
                a3 = fmaf(xv[r][c + 3], kv, a3);
            }
        float* lp = buf + ol * LO + lbase;
        f32x2 v0; v0[0] = a0; v0[1] = a1;
        *reinterpret_cast<f32x2*>(lp) = v0;
        if (!tail) {
            f32x2 v1; v1[0] = a2; v1[1] = a3;
            *reinterpret_cast<f32x2*>(lp + 2) = v1;
        }
    }
}

__device__ __forceinline__ void drain_tile(const float* __restrict__ buf,
                                           float* __restrict__ ob, int f,
                                           bool active)
{
    if (active) {
        f32x4 s0 = *reinterpret_cast<const f32x4*>(buf + 0 * LO + f);
        f32x4 s1 = *reinterpret_cast<const f32x4*>(buf + 1 * LO + f);
        f32x4 s2 = *reinterpret_cast<const f32x4*>(buf + 2 * LO + f);
        f32x4 s3 = *reinterpret_cast<const f32x4*>(buf + 3 * LO + f);
        f32x4 s4 = *reinterpret_cast<const f32x4*>(buf + 4 * LO + f);
        f32x4 s5 = *reinterpret_cast<const f32x4*>(buf + 5 * LO + f);
        f32x4 s6 = *reinterpret_cast<const f32x4*>(buf + 6 * LO + f);
        f32x4 s7 = *reinterpret_cast<const f32x4*>(buf + 7 * LO + f);
        __builtin_nontemporal_store(s0, reinterpret_cast<f32x4*>(ob + (size_t)0 * OHW + f));
        __builtin_nontemporal_store(s1, reinterpret_cast<f32x4*>(ob + (size_t)1 * OHW + f));
        __builtin_nontemporal_store(s2, reinterpret_cast<f32x4*>(ob + (size_t)2 * OHW + f));
        __builtin_nontemporal_store(s3, reinterpret_cast<f32x4*>(ob + (size_t)3 * OHW + f));
        __builtin_nontemporal_store(s4, reinterpret_cast<f32x4*>(ob + (size_t)4 * OHW + f));
        __builtin_nontemporal_store(s5, reinterpret_cast<f32x4*>(ob + (size_t)5 * OHW + f));
        __builtin_nontemporal_store(s6, reinterpret_cast<f32x4*>(ob + (size_t)6 * OHW + f));
        __builtin_nontemporal_store(s7, reinterpret_cast<f32x4*>(ob + (size_t)7 * OHW + f));
    }
}

__global__ __launch_bounds__(256, 2) void conv3x3_k16_kernel(
    const float* __restrict__ x,
    const float* __restrict__ k,
    float* __restrict__ out)
{
    __shared__ float lds[2][PPB * LO];   // 65,280 B

    const int bid  = blockIdx.x;
    const int oh   = bid & 1;
    const int rest = bid >> 1;
    const int band = rest % NBAND;
    const int n    = rest / NBAND;
    const int rp0  = band * TQ;              // first row-pair tile

    const int t    = threadIdx.x;
    const int half = t >> 7;
    const int tt   = t & 127;
    const bool tail = (tt == 127);
    const int ob_f = PPB * oh;

    int j;
    if (half == 0) j = tail ? 508 : 4 * tt;      // even rows
    else           j = tail ? 0   : 4 * tt + 2;  // odd rows
    const int lbase = half * OW + j;
    const int f = 4 * t;                          // drain chunk (t<255)
    const bool active = (t < 255);

    const float* xn = x + (size_t)n * IH * IW;
    float* on = out + ((size_t)(n * KO + ob_f)) * OHW;

    // Prologue: load tile 0.
    float xvA[3][6], xvB[3][6];
    load_xv(xn + (size_t)(2 * rp0 + half) * IW + j, tail, xvA);

#pragma unroll 1
    for (int q = 0; q < TQ; q += 2) {
        // ---- sub-iter A: tile (rp0+q), bank A, buf[0] ----
        {
            const int rp = rp0 + q;
            fma_to_lds(xvA, k, ob_f, &lds[0][0], lbase, tail);
            const int rpn = (q + 1 < TQ) ? rp + 1 : rp;    // clamp
            load_xv(xn + (size_t)(2 * rpn + half) * IW + j, tail, xvB);
            asm volatile("s_waitcnt lgkmcnt(0)" ::: "memory");
            __builtin_amdgcn_sched_barrier(0);
            __builtin_amdgcn_s_barrier();
            __builtin_amdgcn_sched_barrier(0);
            drain_tile(&lds[0][0], on + (size_t)(2 * rp) * OW, f, active);
        }
        // ---- sub-iter B: tile (rp0+q+1), bank B, buf[1] ----
        if (q + 1 < TQ) {
            const int rp = rp0 + q + 1;
            fma_to_lds(xvB, k, ob_f, &lds[1][0], lbase, tail);
            const int rpn = (q + 2 < TQ) ? rp + 1 : rp;    // clamp
            load_xv(xn + (size_t)(2 * rpn + half) * IW + j, tail, xvA);
            asm volatile("s_waitcnt lgkmcnt(0)" ::: "memory");
            __builtin_amdgcn_sched_barrier(0);
            __builtin_amdgcn_s_barrier();
            __builtin_amdgcn_sched_barrier(0);
            drain_tile(&lds[1][0], on + (size_t)(2 * rp) * OW, f, active);
        }
    }
}

extern "C" void kernel_launch(void* const* d_in, const int* in_sizes, int n_in,
                              void* d_out, int out_size, void* d_ws, size_t ws_size,
                              hipStream_t stream) {
    const float* x   = (const float*)d_in[0];
    const float* ker = (const float*)d_in[1];
    float* out       = (float*)d_out;

    dim3 grid(NB * NBAND * 2);   // 1088 blocks: (n, band) x o-half
    dim3 block(256);
    conv3x3_k16_kernel<<<grid, block, 0, stream>>>(x, ker, out);
}

// Round 15
// 118.420 us; speedup vs baseline: 1.3589x; 1.3589x over previous
//
#include <hip/hip_runtime.h>

#define IH 512
#define IW 512
#define OH 510
#define OW 510
#define NB 32
#define KO 16
#define OHW (OH * OW)
#define PPB 8              // planes per block
#define LO 1020            // floats per plane-region in LDS (2 rows x 510)

typedef float f32x4 __attribute__((ext_vector_type(4)));
typedef float f32x2 __attribute__((ext_vector_type(2)));

// R15 = R13 (champion, 121.6us) with ONE change: plain stores instead of
// __builtin_nontemporal_store. A/B on cache policy: nt marks writes
// no-allocate/streaming in L2, plausibly defeating L2 write-combining and
// issuing less-batched DRAM bursts (fill kernel uses PLAIN stores at
// 6.9 TB/s; our nt stores plateau at 4.6). Never tested in the
// write-efficiency regime. Everything else identical to R13.
__global__ __launch_bounds__(256, 4) void conv3x3_k16_kernel(
    const float* __restrict__ x,
    const float* __restrict__ k,
    float* __restrict__ out)
{
    __shared__ float lds[PPB * LO];   // 32,640 B

    const int bid  = blockIdx.x;
    const int oh   = bid & 1;                 // filter half: planes 8*oh..
    const int tile = bid >> 1;
    const int n  = tile / (OH / 2);           // image
    const int i0 = (tile - n * (OH / 2)) * 2; // even base row
    const int t  = threadIdx.x;
    const int half = t >> 7;                  // row within pair
    const int tt = t & 127;
    const int i  = i0 + half;                 // output row
    const bool tail = (tt == 127);

    // Even rows: j=4tt (tail 508); odd rows: j=4tt+2 (tail 0).
    int j;
    if ((i & 1) == 0) j = tail ? 508 : 4 * tt;
    else              j = tail ? 0   : 4 * tt + 2;

    const float* xr = x + ((size_t)n * IH + i) * IW + j;

    // Phase 1: load 3 rows x 6 cols (tail: 3 x 4), 8B-aligned float2s.
    float xv[3][6];
#pragma unroll
    for (int r = 0; r < 3; ++r) {
        const float2 a = *reinterpret_cast<const float2*>(xr + r * IW);
        const float2 b = *reinterpret_cast<const float2*>(xr + r * IW + 2);
        xv[r][0] = a.x; xv[r][1] = a.y; xv[r][2] = b.x; xv[r][3] = b.y;
        if (!tail) {
            const float2 c = *reinterpret_cast<const float2*>(xr + r * IW + 4);
            xv[r][4] = c.x; xv[r][5] = c.y;
        } else {
            xv[r][4] = 0.0f; xv[r][5] = 0.0f;
        }
    }

    // Phase 2: FMA for 8 planes, deposit into LDS.
    const int lbase = half * OW + j;
#pragma unroll
    for (int ol = 0; ol < PPB; ++ol) {
        const int o = PPB * oh + ol;
        float a0 = 0.f, a1 = 0.f, a2 = 0.f, a3 = 0.f;
#pragma unroll
        for (int r = 0; r < 3; ++r)
#pragma unroll
            for (int c = 0; c < 3; ++c) {
                const float kv = k[(o * 3 + r) * 3 + c];  // uniform -> s_load
                a0 = fmaf(xv[r][c],     kv, a0);
                a1 = fmaf(xv[r][c + 1], kv, a1);
                a2 = fmaf(xv[r][c + 2], kv, a2);
                a3 = fmaf(xv[r][c + 3], kv, a3);
            }
        float* lp = &lds[ol * LO + lbase];
        f32x2 v0; v0[0] = a0; v0[1] = a1;
        *reinterpret_cast<f32x2*>(lp) = v0;
        if (!tail) {
            f32x2 v1; v1[0] = a2; v1[1] = a3;
            *reinterpret_cast<f32x2*>(lp + 2) = v1;
        }
    }

    __syncthreads();

    // Phase 3: stream out (plain stores -> L2 write-combining).
    if (t < 255) {
        float* ob = out + (((size_t)(n * KO + PPB * oh)) * OH + i0) * OW;
        const int f = 4 * t;
#pragma unroll
        for (int ol = 0; ol < PPB; ++ol) {
            const f32x4 v = *reinterpret_cast<const f32x4*>(&lds[ol * LO + f]);
            *reinterpret_cast<f32x4*>(ob + (size_t)ol * OHW + f) = v;
        }
    }
}

extern "C" void kernel_launch(void* const* d_in, const int* in_sizes, int n_in,
                              void* d_out, int out_size, void* d_ws, size_t ws_size,
                              hipStream_t stream) {
    const float* x   = (const float*)d_in[0];
    const float* ker = (const float*)d_in[1];
    float* out       = (float*)d_out;

    dim3 grid(NB * (OH / 2) * 2);   // 16320 blocks: (image, row-pair) x o-half
    dim3 block(256);
    conv3x3_k16_kernel<<<grid, block, 0, stream>>>(x, ker, out);
}